// Round 3
// baseline (305.515 us; speedup 1.0000x reference)
//
#include <hip/hip_runtime.h>

#define EPSV 1e-5f

__device__ __forceinline__ float block_reduce_sum(float v, float* lds) {
  #pragma unroll
  for (int off = 32; off > 0; off >>= 1) v += __shfl_down(v, off, 64);
  int lane = threadIdx.x & 63;
  int wid  = threadIdx.x >> 6;
  __syncthreads();
  if (lane == 0) lds[wid] = v;
  __syncthreads();
  float r = 0.f;
  if (threadIdx.x == 0) {
    int nw = blockDim.x >> 6;
    for (int i = 0; i < nw; ++i) r += lds[i];
  }
  return r;
}

// K1: conv1 (recomputed) + per-channel sum/sumsq partials.
__global__ __launch_bounds__(256) void k1_conv1_stats(
    const float* __restrict__ x, const float* __restrict__ w1, const float* __restrict__ b1,
    float* __restrict__ partials /* [16][2][1024] */) {
  __shared__ float lds[4];
  float sum[16], sq[16];
  #pragma unroll
  for (int c = 0; c < 16; ++c) { sum[c] = 0.f; sq[c] = 0.f; }
  const int total = 1024 * 32 * 32;
  for (int e = blockIdx.x * blockDim.x + threadIdx.x; e < total; e += gridDim.x * blockDim.x) {
    int wq = e & 31; int t = e >> 5; int hq = t & 31; int b = t >> 5;
    float xv[3][3][3];
    #pragma unroll
    for (int ci = 0; ci < 3; ++ci) {
      const float* xb = x + (b * 3 + ci) * 1024;
      #pragma unroll
      for (int dy = 0; dy < 3; ++dy) {
        int r = hq + dy - 1;
        #pragma unroll
        for (int dx = 0; dx < 3; ++dx) {
          int cpos = wq + dx - 1;
          xv[ci][dy][dx] = (r >= 0 && r < 32 && cpos >= 0 && cpos < 32) ? xb[r * 32 + cpos] : 0.f;
        }
      }
    }
    #pragma unroll
    for (int co = 0; co < 16; ++co) {
      float a = b1[co];
      #pragma unroll
      for (int ci = 0; ci < 3; ++ci)
        #pragma unroll
        for (int ky = 0; ky < 3; ++ky)
          #pragma unroll
          for (int kx = 0; kx < 3; ++kx)
            a = fmaf(xv[ci][ky][kx], w1[((co * 3 + ci) * 3 + ky) * 3 + kx], a);
      sum[co] += a;
      sq[co]  += a * a;
    }
  }
  for (int c = 0; c < 16; ++c) {
    float s = block_reduce_sum(sum[c], lds);
    float q = block_reduce_sum(sq[c], lds);
    if (threadIdx.x == 0) {
      partials[(c * 2 + 0) * gridDim.x + blockIdx.x] = s;
      partials[(c * 2 + 1) * gridDim.x + blockIdx.x] = q;
    }
  }
}

// K2/K6: reduce partials -> scale/shift per channel.
__global__ __launch_bounds__(256) void k_bn_finalize(
    const float* __restrict__ partials, int nb, float invN,
    const float* __restrict__ gamma, const float* __restrict__ beta,
    float* __restrict__ stats, int C) {
  __shared__ float lds[4];
  int c = blockIdx.x;
  float s = 0.f, q = 0.f;
  for (int i = threadIdx.x; i < nb; i += blockDim.x) {
    s += partials[(c * 2 + 0) * nb + i];
    q += partials[(c * 2 + 1) * nb + i];
  }
  s = block_reduce_sum(s, lds);
  q = block_reduce_sum(q, lds);
  if (threadIdx.x == 0) {
    float mean = s * invN;
    float var  = q * invN - mean * mean;
    float scale = gamma[c] * rsqrtf(var + EPSV);
    stats[c]     = scale;
    stats[C + c] = beta[c] - mean * scale;
  }
}

// K3: conv1 (recomputed) + BN + ReLU + basis_pool(K=2) -> h1 [1024,32,16,16]
__global__ __launch_bounds__(256) void k3_pool1(
    const float* __restrict__ x, const float* __restrict__ w1, const float* __restrict__ b1,
    const float* __restrict__ stats1, const float* __restrict__ pw, const float* __restrict__ pb,
    float* __restrict__ h1) {
  int e = blockIdx.x * 256 + threadIdx.x;
  int ow = e & 15; int t = e >> 4; int oh = t & 15; int b = t >> 4;
  float xv[3][4][4];
  #pragma unroll
  for (int ci = 0; ci < 3; ++ci) {
    const float* xb = x + (b * 3 + ci) * 1024;
    #pragma unroll
    for (int dy = 0; dy < 4; ++dy) {
      int r = 2 * oh - 1 + dy;
      #pragma unroll
      for (int dx = 0; dx < 4; ++dx) {
        int cpos = 2 * ow - 1 + dx;
        xv[ci][dy][dx] = (r >= 0 && r < 32 && cpos >= 0 && cpos < 32) ? xb[r * 32 + cpos] : 0.f;
      }
    }
  }
  float pw0 = pw[0] * 10.f, pw1 = pw[1] * 10.f;
  float pb0 = pb[0] * 10.f, pb1 = pb[1] * 10.f;
  for (int c = 0; c < 16; ++c) {
    float scale = stats1[c], shift = stats1[16 + c];
    float v[4];
    #pragma unroll
    for (int p = 0; p < 4; ++p) {
      int dh = p >> 1, dw = p & 1;
      float a = b1[c];
      #pragma unroll
      for (int ci = 0; ci < 3; ++ci)
        #pragma unroll
        for (int ky = 0; ky < 3; ++ky)
          #pragma unroll
          for (int kx = 0; kx < 3; ++kx)
            a = fmaf(xv[ci][dh + ky][dw + kx], w1[((c * 3 + ci) * 3 + ky) * 3 + kx], a);
      a = fmaf(a, scale, shift);
      v[p] = fmaxf(a, 0.f);
    }
    #pragma unroll
    for (int k = 0; k < 2; ++k) {
      float cw = k ? pw1 : pw0;
      float cb = k ? pb1 : pb0;
      float s0 = fmaf(v[0], cw, cb), s1 = fmaf(v[1], cw, cb);
      float s2 = fmaf(v[2], cw, cb), s3 = fmaf(v[3], cw, cb);
      float m = fmaxf(fmaxf(s0, s1), fmaxf(s2, s3));
      float e0 = expf(s0 - m), e1 = expf(s1 - m), e2 = expf(s2 - m), e3 = expf(s3 - m);
      float den = e0 + e1 + e2 + e3;
      float outv = (v[0] * e0 + v[1] * e1 + v[2] * e2 + v[3] * e3) / den;
      h1[((b * 32 + (c * 2 + k)) * 16 + oh) * 16 + ow] = outv;
    }
  }
}

// K4: conv2 via LDS-staged tile, one block per batch image, all 32 co per thread.
// Fused: per-block partial BN2 stats (sum, sumsq) -> partials [32][2][1024].
__global__ __launch_bounds__(256) void k4_conv2(
    const float* __restrict__ h1, const float* __restrict__ w2, const float* __restrict__ b2,
    float* __restrict__ y2, float* __restrict__ partials) {
  __shared__ float tile[32 * 256 + 64];  // [ci][16x16] + zero slot at 8192 + redzone reuse
  const int tid = threadIdx.x;
  const int b = blockIdx.x;

  // Stage h1[b] (32 KB) into LDS, vectorized.
  {
    const float4* h4 = (const float4*)(h1 + b * 8192);
    float4* t4 = (float4*)tile;
    #pragma unroll
    for (int j = 0; j < 8; ++j) t4[j * 256 + tid] = h4[j * 256 + tid];
  }
  if (tid == 0) tile[8192] = 0.f;
  __syncthreads();

  const int wq = tid & 15, hq = tid >> 4;
  // Precompute 9 neighborhood offsets + validity (pad -> zero slot).
  int off[9];
  bool val[9];
  #pragma unroll
  for (int ky = 0; ky < 3; ++ky) {
    int r = hq + ky - 1;
    #pragma unroll
    for (int kx = 0; kx < 3; ++kx) {
      int c = wq + kx - 1;
      bool ok = ((unsigned)r < 16u) & ((unsigned)c < 16u);
      off[ky * 3 + kx] = ok ? (r * 16 + c) : 0;
      val[ky * 3 + kx] = ok;
    }
  }

  float acc[32];
  #pragma unroll
  for (int co = 0; co < 32; ++co) acc[co] = b2[co];

  for (int ci = 0; ci < 32; ++ci) {
    const int cb = ci * 256;
    float xv[9];
    #pragma unroll
    for (int j = 0; j < 9; ++j) xv[j] = tile[val[j] ? (cb + off[j]) : 8192];
    const float* wp = w2 + ci * 9;  // wave-uniform -> scalar loads
    #pragma unroll
    for (int co = 0; co < 32; ++co) {
      #pragma unroll
      for (int kk = 0; kk < 9; ++kk)
        acc[co] = fmaf(xv[kk], wp[co * 288 + kk], acc[co]);
    }
  }

  // Coalesced write of y2[b].
  {
    float* yb = y2 + b * 8192;
    #pragma unroll
    for (int co = 0; co < 32; ++co) yb[co * 256 + tid] = acc[co];
  }

  // Fused BN2 partial stats: per-channel sum & sumsq over this block's 256 outputs.
  __syncthreads();  // tile reads done; reuse LDS
  const int lane = tid & 63, wid = tid >> 6;
  #pragma unroll
  for (int co = 0; co < 32; ++co) {
    float s = acc[co];
    float q = acc[co] * acc[co];
    #pragma unroll
    for (int o = 32; o > 0; o >>= 1) {
      s += __shfl_down(s, o, 64);
      q += __shfl_down(q, o, 64);
    }
    if (lane == 0) { tile[co * 8 + wid] = s; tile[co * 8 + 4 + wid] = q; }
  }
  __syncthreads();
  if (tid < 64) {
    int co = tid >> 1, sel = tid & 1;
    const float* rp = tile + co * 8 + sel * 4;
    partials[(co * 2 + sel) * 1024 + b] = rp[0] + rp[1] + rp[2] + rp[3];
  }
}

// K7: BN + ReLU + basis_pool2 -> h2 [1024,64,8,8]; one thread per (b,oh,ow).
__global__ __launch_bounds__(256) void k7_pool2(
    const float* __restrict__ y2, const float* __restrict__ stats2,
    const float* __restrict__ pw, const float* __restrict__ pb,
    float* __restrict__ h2) {
  int e = blockIdx.x * 256 + threadIdx.x;
  int ow = e & 7; int t = e >> 3; int oh = t & 7; int b = t >> 3;
  float pw0 = pw[0] * 10.f, pw1 = pw[1] * 10.f;
  float pb0 = pb[0] * 10.f, pb1 = pb[1] * 10.f;
  for (int c = 0; c < 32; ++c) {
    float scale = stats2[c], shift = stats2[32 + c];
    const float* yb = y2 + (b * 32 + c) * 256 + (2 * oh) * 16 + 2 * ow;
    float v0 = fmaxf(fmaf(yb[0],  scale, shift), 0.f);
    float v1 = fmaxf(fmaf(yb[1],  scale, shift), 0.f);
    float v2 = fmaxf(fmaf(yb[16], scale, shift), 0.f);
    float v3 = fmaxf(fmaf(yb[17], scale, shift), 0.f);
    #pragma unroll
    for (int k = 0; k < 2; ++k) {
      float cw = k ? pw1 : pw0;
      float cb = k ? pb1 : pb0;
      float s0 = fmaf(v0, cw, cb), s1 = fmaf(v1, cw, cb);
      float s2 = fmaf(v2, cw, cb), s3 = fmaf(v3, cw, cb);
      float m = fmaxf(fmaxf(s0, s1), fmaxf(s2, s3));
      float e0 = expf(s0 - m), e1 = expf(s1 - m), e2 = expf(s2 - m), e3 = expf(s3 - m);
      float den = e0 + e1 + e2 + e3;
      float outv = (v0 * e0 + v1 * e1 + v2 * e2 + v3 * e3) / den;
      h2[((b * 64 + (c * 2 + k)) * 8 + oh) * 8 + ow] = outv;
    }
  }
}

// K8: FC [1024,4096] x [10,4096]^T + b -> out [1024,10]; one block per row.
__global__ __launch_bounds__(256) void k8_fc(
    const float* __restrict__ h2, const float* __restrict__ fcw,
    const float* __restrict__ fcb, float* __restrict__ out) {
  __shared__ float lds[40];
  int b = blockIdx.x;
  float acc[10];
  #pragma unroll
  for (int j = 0; j < 10; ++j) acc[j] = 0.f;
  const float* hb = h2 + b * 4096;
  for (int i = threadIdx.x; i < 4096; i += 256) {
    float hv = hb[i];
    #pragma unroll
    for (int j = 0; j < 10; ++j) acc[j] = fmaf(hv, fcw[j * 4096 + i], acc[j]);
  }
  int lane = threadIdx.x & 63, wid = threadIdx.x >> 6;
  #pragma unroll
  for (int j = 0; j < 10; ++j) {
    float v = acc[j];
    #pragma unroll
    for (int off = 32; off > 0; off >>= 1) v += __shfl_down(v, off, 64);
    if (lane == 0) lds[wid * 10 + j] = v;
  }
  __syncthreads();
  if (threadIdx.x < 10) {
    float r = lds[threadIdx.x] + lds[10 + threadIdx.x] + lds[20 + threadIdx.x] +
              lds[30 + threadIdx.x] + fcb[threadIdx.x];
    out[b * 10 + threadIdx.x] = r;
  }
}

extern "C" void kernel_launch(void* const* d_in, const int* in_sizes, int n_in,
                              void* d_out, int out_size, void* d_ws, size_t ws_size,
                              hipStream_t stream) {
  (void)in_sizes; (void)n_in; (void)out_size; (void)ws_size;
  const float* x   = (const float*)d_in[0];
  const float* w1  = (const float*)d_in[1];
  const float* b1  = (const float*)d_in[2];
  const float* g1  = (const float*)d_in[3];
  const float* be1 = (const float*)d_in[4];
  const float* pw1 = (const float*)d_in[5];
  const float* pb1 = (const float*)d_in[6];
  const float* w2  = (const float*)d_in[7];
  const float* b2  = (const float*)d_in[8];
  const float* g2  = (const float*)d_in[9];
  const float* be2 = (const float*)d_in[10];
  const float* pw2 = (const float*)d_in[11];
  const float* pb2 = (const float*)d_in[12];
  const float* fcw = (const float*)d_in[13];
  const float* fcb = (const float*)d_in[14];
  float* out = (float*)d_out;

  char* ws = (char*)d_ws;
  float* h1       = (float*)(ws);                         // 32 MiB
  float* y2       = (float*)(ws + 33554432);              // 32 MiB
  float* h2       = (float*)(ws);                         // reuse of h1 space (16 MiB)
  float* partials = (float*)(ws + 67108864);              // 256 KiB (max [32][2][1024])
  float* stats1   = (float*)(ws + 67108864 + 262144);     // 32 floats
  float* stats2   = stats1 + 32;                          // 64 floats

  k1_conv1_stats<<<1024, 256, 0, stream>>>(x, w1, b1, partials);
  k_bn_finalize<<<16, 256, 0, stream>>>(partials, 1024, 1.f / 1048576.f, g1, be1, stats1, 16);
  k3_pool1<<<1024, 256, 0, stream>>>(x, w1, b1, stats1, pw1, pb1, h1);
  k4_conv2<<<1024, 256, 0, stream>>>(h1, w2, b2, y2, partials);
  k_bn_finalize<<<32, 256, 0, stream>>>(partials, 1024, 1.f / 262144.f, g2, be2, stats2, 32);
  k7_pool2<<<256, 256, 0, stream>>>(y2, stats2, pw2, pb2, h2);
  k8_fc<<<1024, 256, 0, stream>>>(h2, fcw, fcb, out);
}

// Round 4
// 236.806 us; speedup vs baseline: 1.2901x; 1.2901x over previous
//
#include <hip/hip_runtime.h>

#define EPSV 1e-5f

__device__ __forceinline__ float block_reduce_sum(float v, float* lds) {
  #pragma unroll
  for (int off = 32; off > 0; off >>= 1) v += __shfl_down(v, off, 64);
  int lane = threadIdx.x & 63;
  int wid  = threadIdx.x >> 6;
  __syncthreads();
  if (lane == 0) lds[wid] = v;
  __syncthreads();
  float r = 0.f;
  if (threadIdx.x == 0) {
    int nw = blockDim.x >> 6;
    for (int i = 0; i < nw; ++i) r += lds[i];
  }
  return r;
}

// K1: conv1 (recomputed) + per-channel sum/sumsq partials.
__global__ __launch_bounds__(256) void k1_conv1_stats(
    const float* __restrict__ x, const float* __restrict__ w1, const float* __restrict__ b1,
    float* __restrict__ partials /* [16][2][1024] */) {
  __shared__ float lds[4];
  float sum[16], sq[16];
  #pragma unroll
  for (int c = 0; c < 16; ++c) { sum[c] = 0.f; sq[c] = 0.f; }
  const int total = 1024 * 32 * 32;
  for (int e = blockIdx.x * blockDim.x + threadIdx.x; e < total; e += gridDim.x * blockDim.x) {
    int wq = e & 31; int t = e >> 5; int hq = t & 31; int b = t >> 5;
    float xv[3][3][3];
    #pragma unroll
    for (int ci = 0; ci < 3; ++ci) {
      const float* xb = x + (b * 3 + ci) * 1024;
      #pragma unroll
      for (int dy = 0; dy < 3; ++dy) {
        int r = hq + dy - 1;
        #pragma unroll
        for (int dx = 0; dx < 3; ++dx) {
          int cpos = wq + dx - 1;
          xv[ci][dy][dx] = (r >= 0 && r < 32 && cpos >= 0 && cpos < 32) ? xb[r * 32 + cpos] : 0.f;
        }
      }
    }
    #pragma unroll
    for (int co = 0; co < 16; ++co) {
      float a = b1[co];
      #pragma unroll
      for (int ci = 0; ci < 3; ++ci)
        #pragma unroll
        for (int ky = 0; ky < 3; ++ky)
          #pragma unroll
          for (int kx = 0; kx < 3; ++kx)
            a = fmaf(xv[ci][ky][kx], w1[((co * 3 + ci) * 3 + ky) * 3 + kx], a);
      sum[co] += a;
      sq[co]  += a * a;
    }
  }
  for (int c = 0; c < 16; ++c) {
    float s = block_reduce_sum(sum[c], lds);
    float q = block_reduce_sum(sq[c], lds);
    if (threadIdx.x == 0) {
      partials[(c * 2 + 0) * gridDim.x + blockIdx.x] = s;
      partials[(c * 2 + 1) * gridDim.x + blockIdx.x] = q;
    }
  }
}

// K2/K6: reduce partials -> scale/shift per channel.
__global__ __launch_bounds__(256) void k_bn_finalize(
    const float* __restrict__ partials, int nb, float invN,
    const float* __restrict__ gamma, const float* __restrict__ beta,
    float* __restrict__ stats, int C) {
  __shared__ float lds[4];
  int c = blockIdx.x;
  float s = 0.f, q = 0.f;
  for (int i = threadIdx.x; i < nb; i += blockDim.x) {
    s += partials[(c * 2 + 0) * nb + i];
    q += partials[(c * 2 + 1) * nb + i];
  }
  s = block_reduce_sum(s, lds);
  q = block_reduce_sum(q, lds);
  if (threadIdx.x == 0) {
    float mean = s * invN;
    float var  = q * invN - mean * mean;
    float scale = gamma[c] * rsqrtf(var + EPSV);
    stats[c]     = scale;
    stats[C + c] = beta[c] - mean * scale;
  }
}

// K3: conv1 (recomputed) + BN + ReLU + basis_pool(K=2) -> h1 [1024,32,16,16]
__global__ __launch_bounds__(256) void k3_pool1(
    const float* __restrict__ x, const float* __restrict__ w1, const float* __restrict__ b1,
    const float* __restrict__ stats1, const float* __restrict__ pw, const float* __restrict__ pb,
    float* __restrict__ h1) {
  int e = blockIdx.x * 256 + threadIdx.x;
  int ow = e & 15; int t = e >> 4; int oh = t & 15; int b = t >> 4;
  float xv[3][4][4];
  #pragma unroll
  for (int ci = 0; ci < 3; ++ci) {
    const float* xb = x + (b * 3 + ci) * 1024;
    #pragma unroll
    for (int dy = 0; dy < 4; ++dy) {
      int r = 2 * oh - 1 + dy;
      #pragma unroll
      for (int dx = 0; dx < 4; ++dx) {
        int cpos = 2 * ow - 1 + dx;
        xv[ci][dy][dx] = (r >= 0 && r < 32 && cpos >= 0 && cpos < 32) ? xb[r * 32 + cpos] : 0.f;
      }
    }
  }
  float pw0 = pw[0] * 10.f, pw1 = pw[1] * 10.f;
  float pb0 = pb[0] * 10.f, pb1 = pb[1] * 10.f;
  for (int c = 0; c < 16; ++c) {
    float scale = stats1[c], shift = stats1[16 + c];
    float v[4];
    #pragma unroll
    for (int p = 0; p < 4; ++p) {
      int dh = p >> 1, dw = p & 1;
      float a = b1[c];
      #pragma unroll
      for (int ci = 0; ci < 3; ++ci)
        #pragma unroll
        for (int ky = 0; ky < 3; ++ky)
          #pragma unroll
          for (int kx = 0; kx < 3; ++kx)
            a = fmaf(xv[ci][dh + ky][dw + kx], w1[((c * 3 + ci) * 3 + ky) * 3 + kx], a);
      a = fmaf(a, scale, shift);
      v[p] = fmaxf(a, 0.f);
    }
    #pragma unroll
    for (int k = 0; k < 2; ++k) {
      float cw = k ? pw1 : pw0;
      float cb = k ? pb1 : pb0;
      float s0 = fmaf(v[0], cw, cb), s1 = fmaf(v[1], cw, cb);
      float s2 = fmaf(v[2], cw, cb), s3 = fmaf(v[3], cw, cb);
      float m = fmaxf(fmaxf(s0, s1), fmaxf(s2, s3));
      float e0 = expf(s0 - m), e1 = expf(s1 - m), e2 = expf(s2 - m), e3 = expf(s3 - m);
      float den = e0 + e1 + e2 + e3;
      float outv = (v[0] * e0 + v[1] * e1 + v[2] * e2 + v[3] * e3) / den;
      h1[((b * 32 + (c * 2 + k)) * 16 + oh) * 16 + ow] = outv;
    }
  }
}

// K4 v3: conv2 via zero-padded LDS tile [32][18][18]; 8 co per thread; grid (1024, 4).
// Fused BN2 partial stats -> partials [32][2][1024].
__global__ __launch_bounds__(256) void k4_conv2(
    const float* __restrict__ h1, const float* __restrict__ w2, const float* __restrict__ b2,
    float* __restrict__ y2, float* __restrict__ partials) {
  __shared__ float tile[11264];  // 32*324 = 10368 used; 44 KB
  const int tid = threadIdx.x;
  const int b = blockIdx.x;
  const int co0 = blockIdx.y * 8;

  // Blanket zero (covers padding), vectorized.
  {
    float4* t4 = (float4*)tile;
    #pragma unroll
    for (int i = 0; i < 11; ++i) {
      int idx = i * 256 + tid;
      if (idx < 2816) t4[idx] = make_float4(0.f, 0.f, 0.f, 0.f);
    }
  }
  __syncthreads();
  // Stage interior: h1[b] (8192 words) into padded layout.
  {
    const float4* h4 = (const float4*)(h1 + b * 8192);
    #pragma unroll
    for (int k = 0; k < 8; ++k) {
      int e4 = k * 256 + tid;            // float4 index
      float4 v = h4[e4];
      int w0 = e4 * 4;                   // word index in [32][256]
      int ch = w0 >> 8;
      int pos = w0 & 255;
      int r = pos >> 4, c = pos & 15;    // c in {0,4,8,12}: same row
      int base = ch * 324 + (r + 1) * 18 + (c + 1);
      tile[base] = v.x; tile[base + 1] = v.y; tile[base + 2] = v.z; tile[base + 3] = v.w;
    }
  }
  __syncthreads();

  const int wq = tid & 15, hq = tid >> 4;
  const int sbase = hq * 18 + wq;
  float acc[8];
  #pragma unroll
  for (int j = 0; j < 8; ++j) acc[j] = b2[co0 + j];

  for (int ci = 0; ci < 32; ++ci) {
    const float* tp = tile + ci * 324 + sbase;
    float xv[9];
    xv[0] = tp[0];  xv[1] = tp[1];  xv[2] = tp[2];
    xv[3] = tp[18]; xv[4] = tp[19]; xv[5] = tp[20];
    xv[6] = tp[36]; xv[7] = tp[37]; xv[8] = tp[38];
    const float* wp = w2 + (co0 * 32 + ci) * 9;  // wave-uniform -> scalar loads
    #pragma unroll
    for (int j = 0; j < 8; ++j) {
      #pragma unroll
      for (int kk = 0; kk < 9; ++kk)
        acc[j] = fmaf(xv[kk], wp[j * 288 + kk], acc[j]);
    }
  }

  // Coalesced write of this co-group.
  {
    float* yb = y2 + (b * 32 + co0) * 256;
    #pragma unroll
    for (int j = 0; j < 8; ++j) yb[j * 256 + tid] = acc[j];
  }

  // Fused BN2 partial stats over this block's 256 positions x 8 channels.
  __syncthreads();  // tile reads done; reuse LDS
  const int lane = tid & 63, wid = tid >> 6;
  #pragma unroll
  for (int j = 0; j < 8; ++j) {
    float s = acc[j];
    float q = acc[j] * acc[j];
    #pragma unroll
    for (int o = 32; o > 0; o >>= 1) {
      s += __shfl_down(s, o, 64);
      q += __shfl_down(q, o, 64);
    }
    if (lane == 0) { tile[j * 8 + wid] = s; tile[j * 8 + 4 + wid] = q; }
  }
  __syncthreads();
  if (tid < 16) {
    int j = tid >> 1, sel = tid & 1;
    const float* rp = tile + j * 8 + sel * 4;
    partials[((co0 + j) * 2 + sel) * 1024 + b] = rp[0] + rp[1] + rp[2] + rp[3];
  }
}

// K7: BN + ReLU + basis_pool2 -> h2 [1024,64,8,8]; one thread per (b,oh,ow).
__global__ __launch_bounds__(256) void k7_pool2(
    const float* __restrict__ y2, const float* __restrict__ stats2,
    const float* __restrict__ pw, const float* __restrict__ pb,
    float* __restrict__ h2) {
  int e = blockIdx.x * 256 + threadIdx.x;
  int ow = e & 7; int t = e >> 3; int oh = t & 7; int b = t >> 3;
  float pw0 = pw[0] * 10.f, pw1 = pw[1] * 10.f;
  float pb0 = pb[0] * 10.f, pb1 = pb[1] * 10.f;
  for (int c = 0; c < 32; ++c) {
    float scale = stats2[c], shift = stats2[32 + c];
    const float* yb = y2 + (b * 32 + c) * 256 + (2 * oh) * 16 + 2 * ow;
    float v0 = fmaxf(fmaf(yb[0],  scale, shift), 0.f);
    float v1 = fmaxf(fmaf(yb[1],  scale, shift), 0.f);
    float v2 = fmaxf(fmaf(yb[16], scale, shift), 0.f);
    float v3 = fmaxf(fmaf(yb[17], scale, shift), 0.f);
    #pragma unroll
    for (int k = 0; k < 2; ++k) {
      float cw = k ? pw1 : pw0;
      float cb = k ? pb1 : pb0;
      float s0 = fmaf(v0, cw, cb), s1 = fmaf(v1, cw, cb);
      float s2 = fmaf(v2, cw, cb), s3 = fmaf(v3, cw, cb);
      float m = fmaxf(fmaxf(s0, s1), fmaxf(s2, s3));
      float e0 = expf(s0 - m), e1 = expf(s1 - m), e2 = expf(s2 - m), e3 = expf(s3 - m);
      float den = e0 + e1 + e2 + e3;
      float outv = (v0 * e0 + v1 * e1 + v2 * e2 + v3 * e3) / den;
      h2[((b * 64 + (c * 2 + k)) * 8 + oh) * 8 + ow] = outv;
    }
  }
}

// K8: FC [1024,4096] x [10,4096]^T + b -> out [1024,10]; one block per row.
__global__ __launch_bounds__(256) void k8_fc(
    const float* __restrict__ h2, const float* __restrict__ fcw,
    const float* __restrict__ fcb, float* __restrict__ out) {
  __shared__ float lds[40];
  int b = blockIdx.x;
  float acc[10];
  #pragma unroll
  for (int j = 0; j < 10; ++j) acc[j] = 0.f;
  const float* hb = h2 + b * 4096;
  for (int i = threadIdx.x; i < 4096; i += 256) {
    float hv = hb[i];
    #pragma unroll
    for (int j = 0; j < 10; ++j) acc[j] = fmaf(hv, fcw[j * 4096 + i], acc[j]);
  }
  int lane = threadIdx.x & 63, wid = threadIdx.x >> 6;
  #pragma unroll
  for (int j = 0; j < 10; ++j) {
    float v = acc[j];
    #pragma unroll
    for (int off = 32; off > 0; off >>= 1) v += __shfl_down(v, off, 64);
    if (lane == 0) lds[wid * 10 + j] = v;
  }
  __syncthreads();
  if (threadIdx.x < 10) {
    float r = lds[threadIdx.x] + lds[10 + threadIdx.x] + lds[20 + threadIdx.x] +
              lds[30 + threadIdx.x] + fcb[threadIdx.x];
    out[b * 10 + threadIdx.x] = r;
  }
}

extern "C" void kernel_launch(void* const* d_in, const int* in_sizes, int n_in,
                              void* d_out, int out_size, void* d_ws, size_t ws_size,
                              hipStream_t stream) {
  (void)in_sizes; (void)n_in; (void)out_size; (void)ws_size;
  const float* x   = (const float*)d_in[0];
  const float* w1  = (const float*)d_in[1];
  const float* b1  = (const float*)d_in[2];
  const float* g1  = (const float*)d_in[3];
  const float* be1 = (const float*)d_in[4];
  const float* pw1 = (const float*)d_in[5];
  const float* pb1 = (const float*)d_in[6];
  const float* w2  = (const float*)d_in[7];
  const float* b2  = (const float*)d_in[8];
  const float* g2  = (const float*)d_in[9];
  const float* be2 = (const float*)d_in[10];
  const float* pw2 = (const float*)d_in[11];
  const float* pb2 = (const float*)d_in[12];
  const float* fcw = (const float*)d_in[13];
  const float* fcb = (const float*)d_in[14];
  float* out = (float*)d_out;

  char* ws = (char*)d_ws;
  float* h1       = (float*)(ws);                         // 32 MiB
  float* y2       = (float*)(ws + 33554432);              // 32 MiB
  float* h2       = (float*)(ws);                         // reuse of h1 space (16 MiB)
  float* partials = (float*)(ws + 67108864);              // 256 KiB (max [32][2][1024])
  float* stats1   = (float*)(ws + 67108864 + 262144);     // 32 floats
  float* stats2   = stats1 + 32;                          // 64 floats

  k1_conv1_stats<<<1024, 256, 0, stream>>>(x, w1, b1, partials);
  k_bn_finalize<<<16, 256, 0, stream>>>(partials, 1024, 1.f / 1048576.f, g1, be1, stats1, 16);
  k3_pool1<<<1024, 256, 0, stream>>>(x, w1, b1, stats1, pw1, pb1, h1);
  dim3 g4(1024, 4);
  k4_conv2<<<g4, 256, 0, stream>>>(h1, w2, b2, y2, partials);
  k_bn_finalize<<<32, 256, 0, stream>>>(partials, 1024, 1.f / 262144.f, g2, be2, stats2, 32);
  k7_pool2<<<256, 256, 0, stream>>>(y2, stats2, pw2, pb2, h2);
  k8_fc<<<1024, 256, 0, stream>>>(h2, fcw, fcb, out);
}

// Round 5
// 218.624 us; speedup vs baseline: 1.3974x; 1.0832x over previous
//
#include <hip/hip_runtime.h>

#define EPSV 1e-5f

__device__ __forceinline__ float block_reduce_sum(float v, float* lds) {
  #pragma unroll
  for (int off = 32; off > 0; off >>= 1) v += __shfl_down(v, off, 64);
  int lane = threadIdx.x & 63;
  int wid  = threadIdx.x >> 6;
  __syncthreads();
  if (lane == 0) lds[wid] = v;
  __syncthreads();
  float r = 0.f;
  if (threadIdx.x == 0) {
    int nw = blockDim.x >> 6;
    for (int i = 0; i < nw; ++i) r += lds[i];
  }
  return r;
}

// K1: conv1 (recomputed) + per-channel sum/sumsq partials.
__global__ __launch_bounds__(256) void k1_conv1_stats(
    const float* __restrict__ x, const float* __restrict__ w1, const float* __restrict__ b1,
    float* __restrict__ partials /* [16][2][1024] */) {
  __shared__ float lds[4];
  float sum[16], sq[16];
  #pragma unroll
  for (int c = 0; c < 16; ++c) { sum[c] = 0.f; sq[c] = 0.f; }
  const int total = 1024 * 32 * 32;
  for (int e = blockIdx.x * blockDim.x + threadIdx.x; e < total; e += gridDim.x * blockDim.x) {
    int wq = e & 31; int t = e >> 5; int hq = t & 31; int b = t >> 5;
    float xv[3][3][3];
    #pragma unroll
    for (int ci = 0; ci < 3; ++ci) {
      const float* xb = x + (b * 3 + ci) * 1024;
      #pragma unroll
      for (int dy = 0; dy < 3; ++dy) {
        int r = hq + dy - 1;
        #pragma unroll
        for (int dx = 0; dx < 3; ++dx) {
          int cpos = wq + dx - 1;
          xv[ci][dy][dx] = (r >= 0 && r < 32 && cpos >= 0 && cpos < 32) ? xb[r * 32 + cpos] : 0.f;
        }
      }
    }
    #pragma unroll
    for (int co = 0; co < 16; ++co) {
      float a = b1[co];
      #pragma unroll
      for (int ci = 0; ci < 3; ++ci)
        #pragma unroll
        for (int ky = 0; ky < 3; ++ky)
          #pragma unroll
          for (int kx = 0; kx < 3; ++kx)
            a = fmaf(xv[ci][ky][kx], w1[((co * 3 + ci) * 3 + ky) * 3 + kx], a);
      sum[co] += a;
      sq[co]  += a * a;
    }
  }
  for (int c = 0; c < 16; ++c) {
    float s = block_reduce_sum(sum[c], lds);
    float q = block_reduce_sum(sq[c], lds);
    if (threadIdx.x == 0) {
      partials[(c * 2 + 0) * gridDim.x + blockIdx.x] = s;
      partials[(c * 2 + 1) * gridDim.x + blockIdx.x] = q;
    }
  }
}

// K2/K6: reduce partials -> scale/shift per channel.
__global__ __launch_bounds__(256) void k_bn_finalize(
    const float* __restrict__ partials, int nb, float invN,
    const float* __restrict__ gamma, const float* __restrict__ beta,
    float* __restrict__ stats, int C) {
  __shared__ float lds[4];
  int c = blockIdx.x;
  float s = 0.f, q = 0.f;
  for (int i = threadIdx.x; i < nb; i += blockDim.x) {
    s += partials[(c * 2 + 0) * nb + i];
    q += partials[(c * 2 + 1) * nb + i];
  }
  s = block_reduce_sum(s, lds);
  q = block_reduce_sum(q, lds);
  if (threadIdx.x == 0) {
    float mean = s * invN;
    float var  = q * invN - mean * mean;
    float scale = gamma[c] * rsqrtf(var + EPSV);
    stats[c]     = scale;
    stats[C + c] = beta[c] - mean * scale;
  }
}

// K3: conv1 (recomputed) + BN + ReLU + basis_pool(K=2) -> h1 [1024,32,16,16]
__global__ __launch_bounds__(256) void k3_pool1(
    const float* __restrict__ x, const float* __restrict__ w1, const float* __restrict__ b1,
    const float* __restrict__ stats1, const float* __restrict__ pw, const float* __restrict__ pb,
    float* __restrict__ h1) {
  int e = blockIdx.x * 256 + threadIdx.x;
  int ow = e & 15; int t = e >> 4; int oh = t & 15; int b = t >> 4;
  float xv[3][4][4];
  #pragma unroll
  for (int ci = 0; ci < 3; ++ci) {
    const float* xb = x + (b * 3 + ci) * 1024;
    #pragma unroll
    for (int dy = 0; dy < 4; ++dy) {
      int r = 2 * oh - 1 + dy;
      #pragma unroll
      for (int dx = 0; dx < 4; ++dx) {
        int cpos = 2 * ow - 1 + dx;
        xv[ci][dy][dx] = (r >= 0 && r < 32 && cpos >= 0 && cpos < 32) ? xb[r * 32 + cpos] : 0.f;
      }
    }
  }
  float pw0 = pw[0] * 10.f, pw1 = pw[1] * 10.f;
  float pb0 = pb[0] * 10.f, pb1 = pb[1] * 10.f;
  for (int c = 0; c < 16; ++c) {
    float scale = stats1[c], shift = stats1[16 + c];
    float v[4];
    #pragma unroll
    for (int p = 0; p < 4; ++p) {
      int dh = p >> 1, dw = p & 1;
      float a = b1[c];
      #pragma unroll
      for (int ci = 0; ci < 3; ++ci)
        #pragma unroll
        for (int ky = 0; ky < 3; ++ky)
          #pragma unroll
          for (int kx = 0; kx < 3; ++kx)
            a = fmaf(xv[ci][dh + ky][dw + kx], w1[((c * 3 + ci) * 3 + ky) * 3 + kx], a);
      a = fmaf(a, scale, shift);
      v[p] = fmaxf(a, 0.f);
    }
    #pragma unroll
    for (int k = 0; k < 2; ++k) {
      float cw = k ? pw1 : pw0;
      float cb = k ? pb1 : pb0;
      float s0 = fmaf(v[0], cw, cb), s1 = fmaf(v[1], cw, cb);
      float s2 = fmaf(v[2], cw, cb), s3 = fmaf(v[3], cw, cb);
      float m = fmaxf(fmaxf(s0, s1), fmaxf(s2, s3));
      float e0 = expf(s0 - m), e1 = expf(s1 - m), e2 = expf(s2 - m), e3 = expf(s3 - m);
      float den = e0 + e1 + e2 + e3;
      float outv = (v[0] * e0 + v[1] * e1 + v[2] * e2 + v[3] * e3) / den;
      h1[((b * 32 + (c * 2 + k)) * 16 + oh) * 16 + ow] = outv;
    }
  }
}

// K4 v4: conv2, one block per image, all 32 co per block.
// Wave w owns co-group w*8..w*8+7; lane s: col c = s&15, rows 4*(s>>4)..+3.
// Per ci: 18 LDS reads feed 288 FMAs. Fused BN2 partial stats (in-wave reduce).
__global__ __launch_bounds__(256) void k4_conv2(
    const float* __restrict__ h1, const float* __restrict__ w2, const float* __restrict__ b2,
    float* __restrict__ y2, float* __restrict__ partials) {
  __shared__ float tile[10368];  // [32][18*18] zero-padded
  const int tid = threadIdx.x;
  const int b = blockIdx.x;

  // Blanket zero (covers padding).
  {
    float4* t4 = (float4*)tile;
    #pragma unroll
    for (int i = 0; i < 11; ++i) {
      int idx = i * 256 + tid;
      if (idx < 2592) t4[idx] = make_float4(0.f, 0.f, 0.f, 0.f);
    }
  }
  __syncthreads();
  // Stage interior: h1[b] into padded layout.
  {
    const float4* h4 = (const float4*)(h1 + b * 8192);
    #pragma unroll
    for (int k = 0; k < 8; ++k) {
      int e4 = k * 256 + tid;
      float4 v = h4[e4];
      int w0 = e4 * 4;
      int ch = w0 >> 8;
      int pos = w0 & 255;
      int r = pos >> 4, c = pos & 15;
      int base = ch * 324 + (r + 1) * 18 + (c + 1);
      tile[base] = v.x; tile[base + 1] = v.y; tile[base + 2] = v.z; tile[base + 3] = v.w;
    }
  }
  __syncthreads();

  const int s = tid & 63;
  const int co0 = (tid >> 6) * 8;       // wave-uniform
  const int c = s & 15;
  const int r0 = (s >> 4) * 4;          // output rows r0..r0+3
  const int sbase = r0 * 18 + c;        // padded window origin

  float acc[32];                        // [j=co][p=row]
  #pragma unroll
  for (int j = 0; j < 8; ++j) {
    float bj = b2[co0 + j];
    #pragma unroll
    for (int p = 0; p < 4; ++p) acc[j * 4 + p] = bj;
  }

  for (int ci = 0; ci < 32; ++ci) {
    const float* tp = tile + ci * 324 + sbase;
    float xv[18];                       // 6 rows x 3 cols
    #pragma unroll
    for (int dr = 0; dr < 6; ++dr) {
      xv[dr * 3 + 0] = tp[dr * 18 + 0];
      xv[dr * 3 + 1] = tp[dr * 18 + 1];
      xv[dr * 3 + 2] = tp[dr * 18 + 2];
    }
    const float* wp = w2 + (co0 * 32 + ci) * 9;  // wave-uniform -> scalar loads
    #pragma unroll
    for (int j = 0; j < 8; ++j) {
      #pragma unroll
      for (int p = 0; p < 4; ++p) {
        #pragma unroll
        for (int ky = 0; ky < 3; ++ky) {
          #pragma unroll
          for (int kx = 0; kx < 3; ++kx)
            acc[j * 4 + p] = fmaf(xv[(p + ky) * 3 + kx], wp[j * 288 + ky * 3 + kx], acc[j * 4 + p]);
        }
      }
    }
  }

  // Write y2 for this wave's co-group.
  {
    float* yb = y2 + b * 8192 + co0 * 256;
    #pragma unroll
    for (int j = 0; j < 8; ++j)
      #pragma unroll
      for (int p = 0; p < 4; ++p)
        yb[j * 256 + (r0 + p) * 16 + c] = acc[j * 4 + p];
  }

  // Fused BN2 partial stats: each wave covers all 256 positions of its 8 channels.
  const int lane = tid & 63;
  #pragma unroll
  for (int j = 0; j < 8; ++j) {
    float a0 = acc[j * 4], a1 = acc[j * 4 + 1], a2 = acc[j * 4 + 2], a3 = acc[j * 4 + 3];
    float sum = a0 + a1 + a2 + a3;
    float sq  = a0 * a0 + a1 * a1 + a2 * a2 + a3 * a3;
    #pragma unroll
    for (int o = 32; o > 0; o >>= 1) {
      sum += __shfl_down(sum, o, 64);
      sq  += __shfl_down(sq, o, 64);
    }
    if (lane == 0) {
      partials[((co0 + j) * 2 + 0) * 1024 + b] = sum;
      partials[((co0 + j) * 2 + 1) * 1024 + b] = sq;
    }
  }
}

// K78: fused BN2-finalized pool2 + FC. One block per image.
__global__ __launch_bounds__(256) void k78_pool2_fc(
    const float* __restrict__ y2, const float* __restrict__ stats2,
    const float* __restrict__ pw, const float* __restrict__ pb,
    const float* __restrict__ fcw, const float* __restrict__ fcb,
    float* __restrict__ out) {
  __shared__ float h2s[4096];
  __shared__ float red[40];
  const int tid = threadIdx.x;
  const int b = blockIdx.x;

  // Pool2: thread -> channel c = tid>>3, row oh = tid&7, all 8 ow.
  {
    const int c = tid >> 3, oh = tid & 7;
    const float scale = stats2[c], shift = stats2[32 + c];
    const float pw0 = pw[0] * 10.f, pw1 = pw[1] * 10.f;
    const float pb0 = pb[0] * 10.f, pb1 = pb[1] * 10.f;
    const float* yb = y2 + (b * 32 + c) * 256 + (2 * oh) * 16;
    float rowa[16], rowb[16];
    #pragma unroll
    for (int k = 0; k < 4; ++k) {
      *(float4*)&rowa[k * 4] = ((const float4*)yb)[k];
      *(float4*)&rowb[k * 4] = ((const float4*)(yb + 16))[k];
    }
    #pragma unroll
    for (int ow = 0; ow < 8; ++ow) {
      float v0 = fmaxf(fmaf(rowa[2 * ow],     scale, shift), 0.f);
      float v1 = fmaxf(fmaf(rowa[2 * ow + 1], scale, shift), 0.f);
      float v2 = fmaxf(fmaf(rowb[2 * ow],     scale, shift), 0.f);
      float v3 = fmaxf(fmaf(rowb[2 * ow + 1], scale, shift), 0.f);
      #pragma unroll
      for (int k = 0; k < 2; ++k) {
        float cw = k ? pw1 : pw0;
        float cb = k ? pb1 : pb0;
        float s0 = fmaf(v0, cw, cb), s1 = fmaf(v1, cw, cb);
        float s2 = fmaf(v2, cw, cb), s3 = fmaf(v3, cw, cb);
        float m = fmaxf(fmaxf(s0, s1), fmaxf(s2, s3));
        float e0 = expf(s0 - m), e1 = expf(s1 - m), e2 = expf(s2 - m), e3 = expf(s3 - m);
        float den = e0 + e1 + e2 + e3;
        h2s[(c * 2 + k) * 64 + oh * 8 + ow] =
            (v0 * e0 + v1 * e1 + v2 * e2 + v3 * e3) / den;
      }
    }
  }
  __syncthreads();

  // FC: out[b][j] = dot(h2s, fcw[j]) + fcb[j]
  float acc[10];
  #pragma unroll
  for (int j = 0; j < 10; ++j) acc[j] = 0.f;
  #pragma unroll
  for (int k = 0; k < 16; ++k) {
    float hv = h2s[k * 256 + tid];
    #pragma unroll
    for (int j = 0; j < 10; ++j)
      acc[j] = fmaf(hv, fcw[j * 4096 + k * 256 + tid], acc[j]);
  }
  const int lane = tid & 63, wid = tid >> 6;
  #pragma unroll
  for (int j = 0; j < 10; ++j) {
    float v = acc[j];
    #pragma unroll
    for (int off = 32; off > 0; off >>= 1) v += __shfl_down(v, off, 64);
    if (lane == 0) red[wid * 10 + j] = v;
  }
  __syncthreads();
  if (tid < 10) {
    out[b * 10 + tid] = red[tid] + red[10 + tid] + red[20 + tid] + red[30 + tid] + fcb[tid];
  }
}

extern "C" void kernel_launch(void* const* d_in, const int* in_sizes, int n_in,
                              void* d_out, int out_size, void* d_ws, size_t ws_size,
                              hipStream_t stream) {
  (void)in_sizes; (void)n_in; (void)out_size; (void)ws_size;
  const float* x   = (const float*)d_in[0];
  const float* w1  = (const float*)d_in[1];
  const float* b1  = (const float*)d_in[2];
  const float* g1  = (const float*)d_in[3];
  const float* be1 = (const float*)d_in[4];
  const float* pw1 = (const float*)d_in[5];
  const float* pb1 = (const float*)d_in[6];
  const float* w2  = (const float*)d_in[7];
  const float* b2  = (const float*)d_in[8];
  const float* g2  = (const float*)d_in[9];
  const float* be2 = (const float*)d_in[10];
  const float* pw2 = (const float*)d_in[11];
  const float* pb2 = (const float*)d_in[12];
  const float* fcw = (const float*)d_in[13];
  const float* fcb = (const float*)d_in[14];
  float* out = (float*)d_out;

  char* ws = (char*)d_ws;
  float* h1       = (float*)(ws);                         // 32 MiB
  float* y2       = (float*)(ws + 33554432);              // 32 MiB
  float* partials = (float*)(ws + 67108864);              // 256 KiB
  float* stats1   = (float*)(ws + 67108864 + 262144);     // 32 floats
  float* stats2   = stats1 + 32;                          // 64 floats

  k1_conv1_stats<<<1024, 256, 0, stream>>>(x, w1, b1, partials);
  k_bn_finalize<<<16, 256, 0, stream>>>(partials, 1024, 1.f / 1048576.f, g1, be1, stats1, 16);
  k3_pool1<<<1024, 256, 0, stream>>>(x, w1, b1, stats1, pw1, pb1, h1);
  k4_conv2<<<1024, 256, 0, stream>>>(h1, w2, b2, y2, partials);
  k_bn_finalize<<<32, 256, 0, stream>>>(partials, 1024, 1.f / 262144.f, g2, be2, stats2, 32);
  k78_pool2_fc<<<1024, 256, 0, stream>>>(y2, stats2, pw2, pb2, fcw, fcb, out);
}

// Round 6
// 194.271 us; speedup vs baseline: 1.5726x; 1.1254x over previous
//
#include <hip/hip_runtime.h>

#define EPSV 1e-5f

__device__ __forceinline__ float block_reduce_sum(float v, float* lds) {
  #pragma unroll
  for (int off = 32; off > 0; off >>= 1) v += __shfl_down(v, off, 64);
  int lane = threadIdx.x & 63;
  int wid  = threadIdx.x >> 6;
  __syncthreads();
  if (lane == 0) lds[wid] = v;
  __syncthreads();
  float r = 0.f;
  if (threadIdx.x == 0) {
    int nw = blockDim.x >> 6;
    for (int i = 0; i < nw; ++i) r += lds[i];
  }
  return r;
}

// Stage x[b] (3x32x32) into zero-padded LDS [3][34][34].
__device__ __forceinline__ void stage_x(const float* __restrict__ x, float* xt, int b, int tid) {
  {
    float4* t4 = (float4*)xt;
    #pragma unroll
    for (int i = 0; i < 4; ++i) {
      int idx = i * 256 + tid;
      if (idx < 867) t4[idx] = make_float4(0.f, 0.f, 0.f, 0.f);
    }
  }
  __syncthreads();
  {
    const float4* x4 = (const float4*)(x + b * 3072);
    #pragma unroll
    for (int k = 0; k < 3; ++k) {
      int e4 = k * 256 + tid;
      float4 v = x4[e4];
      int w0 = e4 * 4;
      int ch = w0 >> 10;
      int pos = w0 & 1023;
      int r = pos >> 5, c = pos & 31;
      int base = ch * 1156 + (r + 1) * 34 + (c + 1);
      xt[base] = v.x; xt[base + 1] = v.y; xt[base + 2] = v.z; xt[base + 3] = v.w;
    }
  }
  __syncthreads();
}

// K1 v2: conv1 via LDS-staged x, one block per image; per-channel stats partials.
// Thread: col c = tid&31, rows r0..r0+3 (r0 = (tid>>5)*4).
__global__ __launch_bounds__(256) void k1_conv1_stats(
    const float* __restrict__ x, const float* __restrict__ w1, const float* __restrict__ b1,
    float* __restrict__ partials /* [16][2][1024] */) {
  __shared__ float xt[3468];
  __shared__ float red[128];
  const int tid = threadIdx.x, b = blockIdx.x;
  stage_x(x, xt, b, tid);

  const int c = tid & 31, r0 = (tid >> 5) * 4;
  const int sbase = r0 * 34 + c;
  float xv[54];  // 3 ci x 6 rows x 3 cols
  #pragma unroll
  for (int ci = 0; ci < 3; ++ci)
    #pragma unroll
    for (int dr = 0; dr < 6; ++dr)
      #pragma unroll
      for (int dx = 0; dx < 3; ++dx)
        xv[ci * 18 + dr * 3 + dx] = xt[ci * 1156 + sbase + dr * 34 + dx];

  const int lane = tid & 63, wid = tid >> 6;
  #pragma unroll
  for (int co = 0; co < 16; ++co) {
    float a0, a1, a2, a3;
    a0 = a1 = a2 = a3 = b1[co];
    #pragma unroll
    for (int ci = 0; ci < 3; ++ci)
      #pragma unroll
      for (int ky = 0; ky < 3; ++ky)
        #pragma unroll
        for (int kx = 0; kx < 3; ++kx) {
          float w = w1[co * 27 + ci * 9 + ky * 3 + kx];
          a0 = fmaf(xv[ci * 18 + (0 + ky) * 3 + kx], w, a0);
          a1 = fmaf(xv[ci * 18 + (1 + ky) * 3 + kx], w, a1);
          a2 = fmaf(xv[ci * 18 + (2 + ky) * 3 + kx], w, a2);
          a3 = fmaf(xv[ci * 18 + (3 + ky) * 3 + kx], w, a3);
        }
    float s = a0 + a1 + a2 + a3;
    float q = fmaf(a0, a0, fmaf(a1, a1, fmaf(a2, a2, a3 * a3)));
    #pragma unroll
    for (int o = 32; o > 0; o >>= 1) {
      s += __shfl_down(s, o, 64);
      q += __shfl_down(q, o, 64);
    }
    if (lane == 0) { red[wid * 32 + co * 2] = s; red[wid * 32 + co * 2 + 1] = q; }
  }
  __syncthreads();
  if (tid < 32) {
    int co = tid >> 1, sel = tid & 1;
    float r = red[co * 2 + sel] + red[32 + co * 2 + sel] +
              red[64 + co * 2 + sel] + red[96 + co * 2 + sel];
    partials[(co * 2 + sel) * 1024 + b] = r;
  }
}

// K2/K6: reduce partials -> scale/shift per channel.
__global__ __launch_bounds__(256) void k_bn_finalize(
    const float* __restrict__ partials, int nb, float invN,
    const float* __restrict__ gamma, const float* __restrict__ beta,
    float* __restrict__ stats, int C) {
  __shared__ float lds[4];
  int c = blockIdx.x;
  float s = 0.f, q = 0.f;
  for (int i = threadIdx.x; i < nb; i += blockDim.x) {
    s += partials[(c * 2 + 0) * nb + i];
    q += partials[(c * 2 + 1) * nb + i];
  }
  s = block_reduce_sum(s, lds);
  q = block_reduce_sum(q, lds);
  if (threadIdx.x == 0) {
    float mean = s * invN;
    float var  = q * invN - mean * mean;
    float scale = gamma[c] * rsqrtf(var + EPSV);
    stats[c]     = scale;
    stats[C + c] = beta[c] - mean * scale;
  }
}

// K3 v2: conv1 (LDS-staged) + BN + ReLU + basis_pool -> h1 [1024,32,16,16].
// One block per image; thread = one 2x2 patch (oh = tid>>4, ow = tid&15).
__global__ __launch_bounds__(256) void k3_pool1(
    const float* __restrict__ x, const float* __restrict__ w1, const float* __restrict__ b1,
    const float* __restrict__ stats1, const float* __restrict__ pw, const float* __restrict__ pb,
    float* __restrict__ h1) {
  __shared__ float xt[3468];
  const int tid = threadIdx.x, b = blockIdx.x;
  stage_x(x, xt, b, tid);

  const int ow = tid & 15, oh = tid >> 4;
  const int wbase = (2 * oh) * 34 + 2 * ow;
  float xv[48];  // 3 ci x 4 rows x 4 cols
  #pragma unroll
  for (int ci = 0; ci < 3; ++ci)
    #pragma unroll
    for (int dr = 0; dr < 4; ++dr)
      #pragma unroll
      for (int dx = 0; dx < 4; ++dx)
        xv[ci * 16 + dr * 4 + dx] = xt[ci * 1156 + wbase + dr * 34 + dx];

  const float pw0 = pw[0] * 10.f, pw1 = pw[1] * 10.f;
  const float pb0 = pb[0] * 10.f, pb1 = pb[1] * 10.f;
  #pragma unroll
  for (int c = 0; c < 16; ++c) {
    const float scale = stats1[c], shift = stats1[16 + c];
    float v[4];
    #pragma unroll
    for (int p = 0; p < 4; ++p) {
      int dh = p >> 1, dw = p & 1;
      float a = b1[c];
      #pragma unroll
      for (int ci = 0; ci < 3; ++ci)
        #pragma unroll
        for (int ky = 0; ky < 3; ++ky)
          #pragma unroll
          for (int kx = 0; kx < 3; ++kx)
            a = fmaf(xv[ci * 16 + (dh + ky) * 4 + (dw + kx)], w1[(c * 3 + ci) * 9 + ky * 3 + kx], a);
      a = fmaf(a, scale, shift);
      v[p] = fmaxf(a, 0.f);
    }
    #pragma unroll
    for (int k = 0; k < 2; ++k) {
      float cw = k ? pw1 : pw0;
      float cb = k ? pb1 : pb0;
      float s0 = fmaf(v[0], cw, cb), s1 = fmaf(v[1], cw, cb);
      float s2 = fmaf(v[2], cw, cb), s3 = fmaf(v[3], cw, cb);
      float m = fmaxf(fmaxf(s0, s1), fmaxf(s2, s3));
      float e0 = expf(s0 - m), e1 = expf(s1 - m), e2 = expf(s2 - m), e3 = expf(s3 - m);
      float den = e0 + e1 + e2 + e3;
      float outv = (v[0] * e0 + v[1] * e1 + v[2] * e2 + v[3] * e3) / den;
      h1[((b * 32 + (c * 2 + k)) * 16 + oh) * 16 + ow] = outv;
    }
  }
}

// K4 v5: conv2 with NO LDS — direct L1/L2 reads of compact h1 via 18 clamped
// offsets + 0/1 multipliers. One block per image; wave w -> co w*8..w*8+7;
// lane: col c = s&15, rows r0..r0+3. Fused BN2 partial stats.
__global__ __launch_bounds__(256) void k4_conv2(
    const float* __restrict__ h1, const float* __restrict__ w2, const float* __restrict__ b2,
    float* __restrict__ y2, float* __restrict__ partials) {
  const int tid = threadIdx.x, b = blockIdx.x;
  const int s = tid & 63;
  const int co0 = (tid >> 6) * 8;   // wave-uniform
  const int c = s & 15, r0 = (s >> 4) * 4;

  int voff[18];
  float vmul[18];
  #pragma unroll
  for (int dr = 0; dr < 6; ++dr) {
    int ir = r0 - 1 + dr;
    int rc = min(max(ir, 0), 15);
    bool rok = ((unsigned)ir < 16u);
    #pragma unroll
    for (int dx = 0; dx < 3; ++dx) {
      int ic = c - 1 + dx;
      int cc = min(max(ic, 0), 15);
      voff[dr * 3 + dx] = rc * 16 + cc;
      vmul[dr * 3 + dx] = (rok && ((unsigned)ic < 16u)) ? 1.f : 0.f;
    }
  }

  const float* hb = h1 + b * 8192;
  float acc[32];  // [j=co][p=row]
  #pragma unroll
  for (int j = 0; j < 8; ++j) {
    float bj = b2[co0 + j];
    #pragma unroll
    for (int p = 0; p < 4; ++p) acc[j * 4 + p] = bj;
  }

  for (int ci = 0; ci < 32; ++ci) {
    const float* p = hb + ci * 256;
    float xv[18];
    #pragma unroll
    for (int j = 0; j < 18; ++j) xv[j] = p[voff[j]] * vmul[j];
    const float* wp = w2 + (co0 * 32 + ci) * 9;  // wave-uniform -> scalar loads
    #pragma unroll
    for (int j = 0; j < 8; ++j) {
      #pragma unroll
      for (int pp = 0; pp < 4; ++pp) {
        #pragma unroll
        for (int ky = 0; ky < 3; ++ky) {
          #pragma unroll
          for (int kx = 0; kx < 3; ++kx)
            acc[j * 4 + pp] = fmaf(xv[(pp + ky) * 3 + kx], wp[j * 288 + ky * 3 + kx], acc[j * 4 + pp]);
        }
      }
    }
  }

  // Write y2 for this wave's co-group.
  {
    float* yb = y2 + b * 8192 + co0 * 256;
    #pragma unroll
    for (int j = 0; j < 8; ++j)
      #pragma unroll
      for (int p = 0; p < 4; ++p)
        yb[j * 256 + (r0 + p) * 16 + c] = acc[j * 4 + p];
  }

  // Fused BN2 partial stats (in-wave shuffle reduce, no LDS).
  const int lane = tid & 63;
  #pragma unroll
  for (int j = 0; j < 8; ++j) {
    float a0 = acc[j * 4], a1 = acc[j * 4 + 1], a2 = acc[j * 4 + 2], a3 = acc[j * 4 + 3];
    float sum = a0 + a1 + a2 + a3;
    float sq  = fmaf(a0, a0, fmaf(a1, a1, fmaf(a2, a2, a3 * a3)));
    #pragma unroll
    for (int o = 32; o > 0; o >>= 1) {
      sum += __shfl_down(sum, o, 64);
      sq  += __shfl_down(sq, o, 64);
    }
    if (lane == 0) {
      partials[((co0 + j) * 2 + 0) * 1024 + b] = sum;
      partials[((co0 + j) * 2 + 1) * 1024 + b] = sq;
    }
  }
}

// K78: fused BN2-finalized pool2 + FC. One block per image.
__global__ __launch_bounds__(256) void k78_pool2_fc(
    const float* __restrict__ y2, const float* __restrict__ stats2,
    const float* __restrict__ pw, const float* __restrict__ pb,
    const float* __restrict__ fcw, const float* __restrict__ fcb,
    float* __restrict__ out) {
  __shared__ float h2s[4096];
  __shared__ float red[40];
  const int tid = threadIdx.x;
  const int b = blockIdx.x;

  {
    const int c = tid >> 3, oh = tid & 7;
    const float scale = stats2[c], shift = stats2[32 + c];
    const float pw0 = pw[0] * 10.f, pw1 = pw[1] * 10.f;
    const float pb0 = pb[0] * 10.f, pb1 = pb[1] * 10.f;
    const float* yb = y2 + (b * 32 + c) * 256 + (2 * oh) * 16;
    float rowa[16], rowb[16];
    #pragma unroll
    for (int k = 0; k < 4; ++k) {
      *(float4*)&rowa[k * 4] = ((const float4*)yb)[k];
      *(float4*)&rowb[k * 4] = ((const float4*)(yb + 16))[k];
    }
    #pragma unroll
    for (int ow = 0; ow < 8; ++ow) {
      float v0 = fmaxf(fmaf(rowa[2 * ow],     scale, shift), 0.f);
      float v1 = fmaxf(fmaf(rowa[2 * ow + 1], scale, shift), 0.f);
      float v2 = fmaxf(fmaf(rowb[2 * ow],     scale, shift), 0.f);
      float v3 = fmaxf(fmaf(rowb[2 * ow + 1], scale, shift), 0.f);
      #pragma unroll
      for (int k = 0; k < 2; ++k) {
        float cw = k ? pw1 : pw0;
        float cb = k ? pb1 : pb0;
        float s0 = fmaf(v0, cw, cb), s1 = fmaf(v1, cw, cb);
        float s2 = fmaf(v2, cw, cb), s3 = fmaf(v3, cw, cb);
        float m = fmaxf(fmaxf(s0, s1), fmaxf(s2, s3));
        float e0 = expf(s0 - m), e1 = expf(s1 - m), e2 = expf(s2 - m), e3 = expf(s3 - m);
        float den = e0 + e1 + e2 + e3;
        h2s[(c * 2 + k) * 64 + oh * 8 + ow] =
            (v0 * e0 + v1 * e1 + v2 * e2 + v3 * e3) / den;
      }
    }
  }
  __syncthreads();

  float acc[10];
  #pragma unroll
  for (int j = 0; j < 10; ++j) acc[j] = 0.f;
  #pragma unroll
  for (int k = 0; k < 16; ++k) {
    float hv = h2s[k * 256 + tid];
    #pragma unroll
    for (int j = 0; j < 10; ++j)
      acc[j] = fmaf(hv, fcw[j * 4096 + k * 256 + tid], acc[j]);
  }
  const int lane = tid & 63, wid = tid >> 6;
  #pragma unroll
  for (int j = 0; j < 10; ++j) {
    float v = acc[j];
    #pragma unroll
    for (int off = 32; off > 0; off >>= 1) v += __shfl_down(v, off, 64);
    if (lane == 0) red[wid * 10 + j] = v;
  }
  __syncthreads();
  if (tid < 10) {
    out[b * 10 + tid] = red[tid] + red[10 + tid] + red[20 + tid] + red[30 + tid] + fcb[tid];
  }
}

extern "C" void kernel_launch(void* const* d_in, const int* in_sizes, int n_in,
                              void* d_out, int out_size, void* d_ws, size_t ws_size,
                              hipStream_t stream) {
  (void)in_sizes; (void)n_in; (void)out_size; (void)ws_size;
  const float* x   = (const float*)d_in[0];
  const float* w1  = (const float*)d_in[1];
  const float* b1  = (const float*)d_in[2];
  const float* g1  = (const float*)d_in[3];
  const float* be1 = (const float*)d_in[4];
  const float* pw1 = (const float*)d_in[5];
  const float* pb1 = (const float*)d_in[6];
  const float* w2  = (const float*)d_in[7];
  const float* b2  = (const float*)d_in[8];
  const float* g2  = (const float*)d_in[9];
  const float* be2 = (const float*)d_in[10];
  const float* pw2 = (const float*)d_in[11];
  const float* pb2 = (const float*)d_in[12];
  const float* fcw = (const float*)d_in[13];
  const float* fcb = (const float*)d_in[14];
  float* out = (float*)d_out;

  char* ws = (char*)d_ws;
  float* h1       = (float*)(ws);                         // 32 MiB
  float* y2       = (float*)(ws + 33554432);              // 32 MiB
  float* partials = (float*)(ws + 67108864);              // 256 KiB
  float* stats1   = (float*)(ws + 67108864 + 262144);     // 32 floats
  float* stats2   = stats1 + 32;                          // 64 floats

  k1_conv1_stats<<<1024, 256, 0, stream>>>(x, w1, b1, partials);
  k_bn_finalize<<<16, 256, 0, stream>>>(partials, 1024, 1.f / 1048576.f, g1, be1, stats1, 16);
  k3_pool1<<<1024, 256, 0, stream>>>(x, w1, b1, stats1, pw1, pb1, h1);
  k4_conv2<<<1024, 256, 0, stream>>>(h1, w2, b2, y2, partials);
  k_bn_finalize<<<32, 256, 0, stream>>>(partials, 1024, 1.f / 262144.f, g2, be2, stats2, 32);
  k78_pool2_fc<<<1024, 256, 0, stream>>>(y2, stats2, pw2, pb2, fcw, fcb, out);
}